// Round 1
// baseline (83.776 us; speedup 1.0000x reference)
//
#include <hip/hip_runtime.h>
#include <math.h>

// SphericalBessel: out[n,kk] = select(x<l, miller_down, upward)(x=r[n]*k[kk]) * sqrt(2/pi)*k[kk]
// l(kk) = floor(sqrt(kk)), K=100 (l_max=9), Miller start l=18.

static constexpr int KMODES = 100;

__device__ __forceinline__ float sbf_elem(float rv, float kv, int l) {
    const float S2PI = 0.7978845608028654f;   // sqrt(2/pi)
    float x = rv * kv;                         // matches reference's f32 x32 for the select
    float inv_x = __builtin_amdgcn_rcpf(x);    // ~1 ulp, fine vs 2.2e-2 threshold
    float s, c;
    sincosf(x, &s, &c);                        // accurate libm this round
    float j0t = s * inv_x;                     // sin(x)/x
    float j1t = (j0t - c) * inv_x;             // (sin/x - cos)/x
    float res;
    if (x < (float)l) {
        // ---- downward (Miller) recurrence, lstart=18, scale-invariant start 1e-18 ----
        float p2 = 0.0f, p1 = 1e-18f, y = 0.0f;
#pragma unroll
        for (int i = 18; i >= 1; --i) {
            float p0 = fmaf((float)(2 * i + 1) * inv_x, p1, -p2);
            if (i - 1 == l) y = p0;            // v_cmp + v_cndmask, no branch
            p2 = p1; p1 = p0;
        }
        // p1 = p at l=0, p2 = p at l=1.
        // Normalize by whichever of j0/j1 is larger in magnitude (avoids the
        // f32 blowup of y/p0*sinc near zeros of sin(x); j0,j1 share no zeros).
        bool use0 = fabsf(j0t) >= fabsf(j1t);
        float pn = use0 ? p1 : p2;
        float jn = use0 ? j0t : j1t;
        res = y * jn * __builtin_amdgcn_rcpf(pn);
    } else {
        // ---- upward recurrence (stable for x >= l) ----
        float jm = j0t, jc = j1t;
        res = (l == 0) ? j0t : j1t;
#pragma unroll
        for (int i = 1; i <= 8; ++i) {
            float j2 = fmaf((float)(2 * i + 1) * inv_x, jc, -jm);
            jm = jc; jc = j2;
            if (l == i + 1) res = jc;          // cndmask capture
        }
    }
    return res * (S2PI * kv);
}

__global__ __launch_bounds__(256) void sbf_kernel(const float* __restrict__ r,
                                                  const float* __restrict__ kv,
                                                  float* __restrict__ out,
                                                  int total) {
    int g0 = blockIdx.x * 512 + threadIdx.x;   // 2 elements per thread, coalesced
#pragma unroll
    for (int e = 0; e < 2; ++e) {
        int g = g0 + e * 256;
        if (g < total) {
            unsigned ug = (unsigned)g;
            unsigned n  = ug / (unsigned)KMODES;       // magic-mul (compile-time 100)
            unsigned kk = ug - n * (unsigned)KMODES;
            int l = (int)sqrtf((float)kk);
            if ((l + 1) * (l + 1) <= (int)kk) ++l;     // guard sqrt rounding
            if (l * l > (int)kk) --l;
            out[g] = sbf_elem(r[n], kv[kk], l);
        }
    }
}

extern "C" void kernel_launch(void* const* d_in, const int* in_sizes, int n_in,
                              void* d_out, int out_size, void* d_ws, size_t ws_size,
                              hipStream_t stream) {
    const float* r = (const float*)d_in[0];
    const float* k = (const float*)d_in[1];
    float* out = (float*)d_out;
    int total = out_size;                      // N * K = 262144 * 100
    int blocks = (total + 511) / 512;
    sbf_kernel<<<blocks, 256, 0, stream>>>(r, k, out, total);
}

// Round 2
// 47.905 us; speedup vs baseline: 1.7488x; 1.7488x over previous
//
#include <hip/hip_runtime.h>
#include <math.h>

// SphericalBessel: out[n,kk] = select(x<l, miller_down, upward)(x=r[n]*k[kk]) * sqrt(2/pi)*k[kk]
// l(kk) = floor(sqrt(kk)), K=100 (l_max=9). Miller start L=13 (trunc err <=5e-4 rel, see journal).
// Native v_sin/v_cos sincos (err ~1e-5, fits 2.17e-2 absmax budget with 10x margin).

static constexpr int KMODES = 100;
static constexpr int ELEMS  = 4;   // elements per thread, strided by N/4 in n (same kk -> shared l,k)

__device__ __forceinline__ float sbf_one(float x, int l, float kv) {
    const float S2PI = 0.7978845608028654f;   // sqrt(2/pi)
    float inv_x = __builtin_amdgcn_rcpf(x);
    float s = __sinf(x);                      // v_mul + v_sin_f32 (x <= 100 -> in HW range)
    float c = __cosf(x);
    float j0t = s * inv_x;                    // sin(x)/x
    float j1t = (j0t - c) * inv_x;
    float res;
    if (x < (float)l) {
        // Miller downward from L=13, scale-invariant start 1e-18 (max growth ~6e29 -> 6e11, in f32 range)
        float p2 = 0.0f, p1 = 1e-18f, y = 0.0f;
#pragma unroll
        for (int i = 13; i >= 1; --i) {
            float p0 = fmaf((float)(2 * i + 1) * inv_x, p1, -p2);
            if (i - 1 == l) y = p0;           // cndmask capture (only l in [1,9] reachable here)
            p2 = p1; p1 = p0;
        }
        // normalize by whichever of j0/j1 is larger (no common zeros -> no f32 blowup near sin(x)=0)
        bool use0 = fabsf(j0t) >= fabsf(j1t);
        float pn = use0 ? p1 : p2;            // p1 = p@l0, p2 = p@l1
        float jn = use0 ? j0t : j1t;
        res = y * jn * __builtin_amdgcn_rcpf(pn);
    } else {
        float jm = j0t, jc = j1t;
        res = (l == 0) ? j0t : j1t;
#pragma unroll
        for (int i = 1; i <= 8; ++i) {
            float j2 = fmaf((float)(2 * i + 1) * inv_x, jc, -jm);
            jm = jc; jc = j2;
            if (l == i + 1) res = jc;
        }
    }
    return res * (S2PI * kv);
}

__global__ __launch_bounds__(256) void sbf_kernel(const float* __restrict__ r,
                                                  const float* __restrict__ kvec,
                                                  float* __restrict__ out,
                                                  int nstride) {   // nstride = N/ELEMS
    int g = blockIdx.x * 256 + threadIdx.x;          // g in [0, nstride*KMODES)
    unsigned ug = (unsigned)g;
    unsigned n  = ug / (unsigned)KMODES;             // magic-mul (constant 100)
    unsigned kk = ug - n * (unsigned)KMODES;
    int l = (int)sqrtf((float)kk);
    if ((l + 1) * (l + 1) <= (int)kk) ++l;           // guard sqrt rounding
    if (l * l > (int)kk) --l;
    float kv = kvec[kk];

    float rv[ELEMS];
#pragma unroll
    for (int e = 0; e < ELEMS; ++e) rv[e] = r[n + e * nstride];

    size_t ostride = (size_t)nstride * (size_t)KMODES;
#pragma unroll
    for (int e = 0; e < ELEMS; ++e) {
        float x = rv[e] * kv;
        out[(size_t)g + (size_t)e * ostride] = sbf_one(x, l, kv);
    }
}

extern "C" void kernel_launch(void* const* d_in, const int* in_sizes, int n_in,
                              void* d_out, int out_size, void* d_ws, size_t ws_size,
                              hipStream_t stream) {
    const float* r = (const float*)d_in[0];
    const float* k = (const float*)d_in[1];
    float* out = (float*)d_out;
    int N = in_sizes[0];                   // 262144, divisible by ELEMS
    int nstride = N / ELEMS;               // 65536
    int threads = nstride * KMODES;        // 6,553,600
    int blocks = threads / 256;            // 25600 (exact)
    sbf_kernel<<<blocks, 256, 0, stream>>>(r, k, out, nstride);
}

// Round 3
// 32.115 us; speedup vs baseline: 2.6087x; 1.4917x over previous
//
#include <hip/hip_runtime.h>
#include <math.h>

// SphericalBessel, l-specialized: block = 4 waves x 64 lanes; lanes <-> n (64-n tile),
// each wave owns a static l-set, l is a template constant -> no capture cndmasks,
// exact loop lengths, scalar k. Results staged in LDS, flushed coalesced (float4).
// Miller start L=l+4: trunc rel err <= 5.7e-4 (l=9, x->9), ~1e-5 for small l.

static constexpr int KMODES = 100;
static constexpr int NTILE  = 64;
static constexpr float S2PI = 0.7978845608028654f;  // sqrt(2/pi)

__device__ __forceinline__ float rcpf(float x) { return __builtin_amdgcn_rcpf(x); }

template<int L>
__device__ __forceinline__ void do_l(float rv, const float* __restrict__ kvec,
                                     float* lds, int lane) {
#pragma unroll
    for (int m = 0; m < 2 * L + 1; ++m) {
        const int KK = L * L + m;
        float kv = kvec[KK];                 // uniform address -> scalar load
        float x = rv * kv;
        float inv_x = rcpf(x);
        float s = __sinf(x);
        float res;
        if constexpr (L == 0) {
            res = s * inv_x;                 // j0 = sin(x)/x
        } else {
            float c = __cosf(x);
            float j0t = s * inv_x;
            float j1t = (j0t - c) * inv_x;
            if constexpr (L == 1) {
                res = j1t;                   // direct j1 fine for all x>=0.05 (cancellation ~1e-5)
            } else {
                // upward recurrence, exactly L-1 iters (valid where x >= L)
                float jm = j0t, jc = j1t;
#pragma unroll
                for (int i = 1; i < L; ++i) {
                    float j2 = fmaf((float)(2 * i + 1) * inv_x, jc, -jm);
                    jm = jc; jc = j2;
                }
                res = jc;
                if (x < (float)L) {          // Miller downward, start L+4; execz-skipped if no lane
                    float p2 = 0.f, p1 = 1e-18f, y = 0.f;
#pragma unroll
                    for (int i = L + 4; i >= 1; --i) {
                        float p0 = fmaf((float)(2 * i + 1) * inv_x, p1, -p2);
                        if (i - 1 == L) y = p0;   // compile-time fold, zero cost
                        p2 = p1; p1 = p0;
                    }
                    // normalize by larger of j0/j1 (no common zeros -> no f32 blowup)
                    bool use0 = fabsf(j0t) >= fabsf(j1t);
                    float pn = use0 ? p1 : p2;    // p1 = p@l0, p2 = p@l1
                    float jn = use0 ? j0t : j1t;
                    res = y * jn * rcpf(pn);
                }
            }
        }
        lds[lane * KMODES + KK] = res * (S2PI * kv);  // vaddr=lane*400 hoisted, offset KK*4 imm
    }
}

__global__ __launch_bounds__(256) void sbf_kernel(const float* __restrict__ r,
                                                  const float* __restrict__ kvec,
                                                  float* __restrict__ out) {
    __shared__ float lds[NTILE * KMODES];    // 25.6 KB -> 6 blocks/CU
    int tid = threadIdx.x;
    int w = tid >> 6, lane = tid & 63;
    int n0 = blockIdx.x * NTILE;
    float rv = r[n0 + lane];                 // coalesced, L1-resident across waves
    // balanced l-partition: elem counts 24/24/25/27
    if (w == 0)      { do_l<9>(rv, kvec, lds, lane); do_l<2>(rv, kvec, lds, lane); }
    else if (w == 1) { do_l<8>(rv, kvec, lds, lane); do_l<3>(rv, kvec, lds, lane); }
    else if (w == 2) { do_l<7>(rv, kvec, lds, lane); do_l<4>(rv, kvec, lds, lane); do_l<0>(rv, kvec, lds, lane); }
    else             { do_l<6>(rv, kvec, lds, lane); do_l<5>(rv, kvec, lds, lane); do_l<1>(rv, kvec, lds, lane); }
    __syncthreads();
    // coalesced flush: 6400 floats, 256 threads x float4 x 7 iters (last partial)
    size_t base = (size_t)n0 * KMODES;
#pragma unroll
    for (int it = 0; it < 7; ++it) {
        int e = it * 1024 + tid * 4;
        if (e < NTILE * KMODES) {
            float4 v = *reinterpret_cast<const float4*>(&lds[e]);
            *reinterpret_cast<float4*>(&out[base + e]) = v;
        }
    }
}

extern "C" void kernel_launch(void* const* d_in, const int* in_sizes, int n_in,
                              void* d_out, int out_size, void* d_ws, size_t ws_size,
                              hipStream_t stream) {
    const float* r = (const float*)d_in[0];
    const float* k = (const float*)d_in[1];
    float* out = (float*)d_out;
    int N = in_sizes[0];                     // 262144, divisible by NTILE
    int blocks = N / NTILE;                  // 4096
    sbf_kernel<<<blocks, 256, 0, stream>>>(r, k, out);
}

// Round 5
// 28.477 us; speedup vs baseline: 2.9419x; 1.1278x over previous
//
#include <hip/hip_runtime.h>
#include <math.h>

// SphericalBessel via compile-time polynomials, l-specialized waves.
// x>=l: closed form j_l = s*S_l(u) + c*C_l(u), u=1/x, z=u^2 (exact integer coeffs,
//        verified against recurrence j_{l+1}=(2l+1)u*j_l - j_{l-1}).
// x< l: Taylor series x^l * Horner(y=x^2), NT=L+3 terms (worst trunc ~5e-6 rel at l=9,x->9).
// LDS staging row stride 101 words (odd -> ds_write conflict-free), b32-quad flush reads.

static constexpr int KMODES = 100;
static constexpr int NTILE  = 64;
static constexpr int LSTRIDE = 101;                 // padded row stride (words)
static constexpr float S2PI = 0.79788456080286536f; // sqrt(2/pi)

__device__ __forceinline__ float rcpf(float x) { return __builtin_amdgcn_rcpf(x); }

// ---- closed-form coefficient tables (polys in z = 1/x^2, highest degree first) ----
// odd  L: j = s*z*sg(z) + c*u*gm(z)
// even L: j = s*u*sg(z) + c*z*gm(z)
template<int L> struct CFc;
template<> struct CFc<2>{ static constexpr float sg[2]={3.f,-1.f};                                   static constexpr float gm[1]={-3.f}; };
template<> struct CFc<3>{ static constexpr float sg[2]={15.f,-6.f};                                  static constexpr float gm[2]={-15.f,1.f}; };
template<> struct CFc<4>{ static constexpr float sg[3]={105.f,-45.f,1.f};                            static constexpr float gm[2]={-105.f,10.f}; };
template<> struct CFc<5>{ static constexpr float sg[3]={945.f,-420.f,15.f};                          static constexpr float gm[3]={-945.f,105.f,-1.f}; };
template<> struct CFc<6>{ static constexpr float sg[4]={10395.f,-4725.f,210.f,-1.f};                 static constexpr float gm[3]={-10395.f,1260.f,-21.f}; };
template<> struct CFc<7>{ static constexpr float sg[4]={135135.f,-62370.f,3150.f,-28.f};             static constexpr float gm[4]={-135135.f,17325.f,-378.f,1.f}; };
template<> struct CFc<8>{ static constexpr float sg[5]={2027025.f,-945945.f,51975.f,-630.f,1.f};     static constexpr float gm[4]={-2027025.f,270270.f,-6930.f,36.f}; };
template<> struct CFc<9>{ static constexpr float sg[5]={34459425.f,-16216200.f,945945.f,-13860.f,45.f}; static constexpr float gm[5]={-34459425.f,4729725.f,-135135.f,990.f,-1.f}; };

// ---- small-x series coefficients: j_l(x) = x^l * sum_k c_k x^{2k},
//      c_k = (-1)^k / (2^k k! (2l+1)!! prod_{j=1..k}(2l+2j+1)), generated constexpr ----
template<int L, int NT> struct SerTab {
  float c[NT];
  constexpr SerTab() : c{} {
    for (int k = 0; k < NT; ++k) {
      double v = 1.0;
      for (int j = 1; j <= L; ++j) v /= (double)(2*j + 1);
      for (int j = 1; j <= k; ++j) v *= -1.0 / (2.0 * j * (double)(2*L + 2*j + 1));
      c[k] = (float)v;
    }
  }
};

template<int N>
__device__ __forceinline__ float polyH(float z, const float (&a)[N]) {
  float h = a[0];
#pragma unroll
  for (int i = 1; i < N; ++i) h = fmaf(h, z, a[i]);
  return h;
}

template<int L> __device__ __forceinline__ float powx(float x, float y) {
  if constexpr (L == 1) return x;
  else if constexpr (L == 2) return y;
  else if constexpr (L == 3) return y * x;
  else if constexpr (L == 4) return y * y;
  else if constexpr (L == 5) return (y * y) * x;
  else if constexpr (L == 6) { float y2 = y * y; return y2 * y; }
  else if constexpr (L == 7) { float y2 = y * y; return (y2 * y) * x; }
  else if constexpr (L == 8) { float y2 = y * y; return y2 * y2; }
  else { float y2 = y * y; float y4 = y2 * y2; return y4 * x; }  // L==9
}

template<int L>
__device__ __forceinline__ void do_l(float rv, float invr,
                                     const float* __restrict__ kvec,
                                     const float* invk, float* ldsrow) {
  constexpr int NT = L + 3;
  constexpr SerTab<L, NT> st{};
#pragma unroll
  for (int m = 0; m < 2 * L + 1; ++m) {
    const int KK = L * L + m;
    float kv = kvec[KK];                 // uniform -> s_load
    float x  = rv * kv;
    float u  = invr * invk[KK];          // 1/x via rcp(r)*rcp(k); ds broadcast + v_mul
    float res;
    if constexpr (L == 0) {
      res = __sinf(x) * u;               // j0 = sin(x)/x
    } else {
      float s = __sinf(x), c = __cosf(x);
      float z = u * u;
      if constexpr (L == 1) {
        res = fmaf(s, z, -(c * u));      // j1 = s/x^2 - c/x
      } else {
        float sv = polyH(z, CFc<L>::sg);
        float gv = polyH(z, CFc<L>::gm);
        if constexpr (L & 1) res = fmaf(s * z, sv, (c * u) * gv);
        else                 res = fmaf(s * u, sv, (c * z) * gv);
      }
      if (x < (float)L) {                // small-x: Taylor series (exec-masked)
        float y = x * x;
        float h = st.c[NT - 1];
#pragma unroll
        for (int t = NT - 2; t >= 0; --t) h = fmaf(h, y, st.c[t]);
        res = h * powx<L>(x, y);
      }
    }
    ldsrow[KK] = res * (S2PI * kv);      // stride-101 row: conflict-free ds_write
  }
}

__global__ __launch_bounds__(256) void sbf_kernel(const float* __restrict__ r,
                                                  const float* __restrict__ kvec,
                                                  float* __restrict__ out) {
  __shared__ float invk[KMODES];
  __shared__ float lds[NTILE * LSTRIDE];   // 25.86 KB -> 6 blocks/CU
  int tid = threadIdx.x;
  if (tid < KMODES) invk[tid] = rcpf(kvec[tid]);
  int w = tid >> 6, lane = tid & 63;
  int n0 = blockIdx.x * NTILE;
  float rv = r[n0 + lane];
  float invr = rcpf(rv);
  float* ldsrow = &lds[lane * LSTRIDE];
  __syncthreads();                          // invk ready
  // cost-balanced l-partition (op-count model): 923/869/906/818 units
  if (w == 0)      { do_l<9>(rv, invr, kvec, invk, ldsrow); do_l<2>(rv, invr, kvec, invk, ldsrow); }
  else if (w == 1) { do_l<8>(rv, invr, kvec, invk, ldsrow); do_l<3>(rv, invr, kvec, invk, ldsrow); do_l<0>(rv, invr, kvec, invk, ldsrow); }
  else if (w == 2) { do_l<7>(rv, invr, kvec, invk, ldsrow); do_l<4>(rv, invr, kvec, invk, ldsrow); do_l<1>(rv, invr, kvec, invk, ldsrow); }
  else             { do_l<6>(rv, invr, kvec, invk, ldsrow); do_l<5>(rv, invr, kvec, invk, ldsrow); }
  __syncthreads();
  // flush: 6400 floats; thread t -> float4 at flat e; padded-row gather (b32 reads, ~2-way)
  size_t base = (size_t)n0 * KMODES;
#pragma unroll
  for (int it = 0; it < 7; ++it) {
    int e = it * 1024 + tid * 4;
    if (e < NTILE * KMODES) {
      int row = (int)((unsigned)e / 100u);   // magic-mul
      int col = e - row * 100;               // col in {0,4,...,96}, float4 stays in-row
      int a = row * LSTRIDE + col;
      float4 v = make_float4(lds[a], lds[a + 1], lds[a + 2], lds[a + 3]);
      *reinterpret_cast<float4*>(&out[base + e]) = v;
    }
  }
}

extern "C" void kernel_launch(void* const* d_in, const int* in_sizes, int n_in,
                              void* d_out, int out_size, void* d_ws, size_t ws_size,
                              hipStream_t stream) {
  const float* r = (const float*)d_in[0];
  const float* k = (const float*)d_in[1];
  float* out = (float*)d_out;
  int N = in_sizes[0];                   // 262144
  int blocks = N / NTILE;                // 4096
  sbf_kernel<<<blocks, 256, 0, stream>>>(r, k, out);
}

// Round 6
// 26.814 us; speedup vs baseline: 3.1243x; 1.0620x over previous
//
#include <hip/hip_runtime.h>
#include <math.h>

// SphericalBessel, closed-form everywhere except a single-term Taylor tail.
// x >= T_l: j_l = s*S_l(z) + c*C_l(z), z=1/x^2 (exact integer coeffs).
// x <  T_l: j_l ~= x^l/(2l+1)!!  (one term; |j_l| <= 2e-5 there, abs-err <= 3e-6).
// T_l set where f32 cancellation err of closed form ~5e-4: eps*(2l-1)!!/T^{l+1}.
// Branchless select -> no exec-mask divergence, no Horner loop.
// LDS staging rows stride 101 (conflict-free ds_write), coalesced float4 flush.

static constexpr int KMODES = 100;
static constexpr int NTILE  = 64;
static constexpr int LSTRIDE = 101;
static constexpr float S2PI = 0.79788456080286536f; // sqrt(2/pi)

__device__ __forceinline__ float rcpf(float x) { return __builtin_amdgcn_rcpf(x); }

// closed-form polys in z = 1/x^2 (highest degree first):
// odd  L: j = s*z*sg(z) + c*u*gm(z);  even L: j = s*u*sg(z) + c*z*gm(z)
template<int L> struct CFc;
template<> struct CFc<2>{ static constexpr float sg[2]={3.f,-1.f};                                      static constexpr float gm[1]={-3.f}; };
template<> struct CFc<3>{ static constexpr float sg[2]={15.f,-6.f};                                     static constexpr float gm[2]={-15.f,1.f}; };
template<> struct CFc<4>{ static constexpr float sg[3]={105.f,-45.f,1.f};                               static constexpr float gm[2]={-105.f,10.f}; };
template<> struct CFc<5>{ static constexpr float sg[3]={945.f,-420.f,15.f};                             static constexpr float gm[3]={-945.f,105.f,-1.f}; };
template<> struct CFc<6>{ static constexpr float sg[4]={10395.f,-4725.f,210.f,-1.f};                    static constexpr float gm[3]={-10395.f,1260.f,-21.f}; };
template<> struct CFc<7>{ static constexpr float sg[4]={135135.f,-62370.f,3150.f,-28.f};                static constexpr float gm[4]={-135135.f,17325.f,-378.f,1.f}; };
template<> struct CFc<8>{ static constexpr float sg[5]={2027025.f,-945945.f,51975.f,-630.f,1.f};        static constexpr float gm[4]={-2027025.f,270270.f,-6930.f,36.f}; };
template<> struct CFc<9>{ static constexpr float sg[5]={34459425.f,-16216200.f,945945.f,-13860.f,45.f}; static constexpr float gm[5]={-34459425.f,4729725.f,-135135.f,990.f,-1.f}; };

// per-l switch point and single-term coefficient 1/(2l+1)!!
__device__ __constant__ const float TTAB[10] = {0.f,0.f,0.12f,0.30f,0.57f,0.92f,1.32f,1.78f,2.30f,2.80f};
__device__ __constant__ const float C0TAB[10] = {1.f, 0.33333333f, 0.066666667f, 0.0095238095f,
  0.0010582011f, 9.6200096e-5f, 7.4000740e-6f, 4.9333827e-7f, 2.9019383e-8f, 1.5273506e-9f};

template<int N>
__device__ __forceinline__ float polyH(float z, const float (&a)[N]) {
  float h = a[0];
#pragma unroll
  for (int i = 1; i < N; ++i) h = fmaf(h, z, a[i]);
  return h;
}

template<int L> __device__ __forceinline__ float powx(float x, float y) {
  if constexpr (L == 2) return y;
  else if constexpr (L == 3) return y * x;
  else if constexpr (L == 4) return y * y;
  else if constexpr (L == 5) return (y * y) * x;
  else if constexpr (L == 6) { float y2 = y * y; return y2 * y; }
  else if constexpr (L == 7) { float y2 = y * y; return (y2 * y) * x; }
  else if constexpr (L == 8) { float y2 = y * y; return y2 * y2; }
  else { float y2 = y * y; float y4 = y2 * y2; return y4 * x; }  // L==9
}

template<int L>
__device__ __forceinline__ void do_l(float rv, float invr,
                                     const float* __restrict__ kvec,
                                     const float* invk, float* ldsrow) {
#pragma unroll
  for (int m = 0; m < 2 * L + 1; ++m) {
    const int KK = L * L + m;
    float kv = kvec[KK];                 // uniform -> scalar load
    float x  = rv * kv;
    float u  = invr * invk[KK];          // 1/x
    float res;
    if constexpr (L == 0) {
      res = __sinf(x) * u;               // j0
    } else {
      float s, c;
      __sincosf(x, &s, &c);
      float z = u * u;
      if constexpr (L == 1) {
        res = fmaf(s, z, -(c * u));      // j1 (no small-x path needed: err<5e-5 at x=0.05)
      } else {
        float sv = polyH(z, CFc<L>::sg);
        float gv = polyH(z, CFc<L>::gm);
        if constexpr (L & 1) res = fmaf(s * z, sv, (c * u) * gv);
        else                 res = fmaf(s * u, sv, (c * z) * gv);
        float y  = x * x;
        float sm = C0TAB[L] * powx<L>(x, y);   // single Taylor term
        res = (x < TTAB[L]) ? sm : res;        // branchless cndmask
      }
    }
    ldsrow[KK] = res * (S2PI * kv);
  }
}

__global__ __launch_bounds__(256) void sbf_kernel(const float* __restrict__ r,
                                                  const float* __restrict__ kvec,
                                                  float* __restrict__ out) {
  __shared__ float invk[KMODES];
  __shared__ float lds[NTILE * LSTRIDE];   // 25.86 KB -> 6 blocks/CU
  int tid = threadIdx.x;
  if (tid < KMODES) invk[tid] = rcpf(kvec[tid]);
  int w = tid >> 6, lane = tid & 63;
  int n0 = blockIdx.x * NTILE;
  float rv = r[n0 + lane];
  float invr = rcpf(rv);
  float* ldsrow = &lds[lane * LSTRIDE];
  __syncthreads();                          // invk ready
  // cost-balanced partition (new op model, VALU + 4*trans): 657/621/606/637
  if (w == 0)      { do_l<9>(rv, invr, kvec, invk, ldsrow); do_l<2>(rv, invr, kvec, invk, ldsrow); }
  else if (w == 1) { do_l<8>(rv, invr, kvec, invk, ldsrow); do_l<3>(rv, invr, kvec, invk, ldsrow); }
  else if (w == 2) { do_l<7>(rv, invr, kvec, invk, ldsrow); do_l<4>(rv, invr, kvec, invk, ldsrow); do_l<0>(rv, invr, kvec, invk, ldsrow); }
  else             { do_l<6>(rv, invr, kvec, invk, ldsrow); do_l<5>(rv, invr, kvec, invk, ldsrow); do_l<1>(rv, invr, kvec, invk, ldsrow); }
  __syncthreads();
  // flush: 6400 floats; padded-row gather (b32 reads), coalesced float4 global store
  size_t base = (size_t)n0 * KMODES;
#pragma unroll
  for (int it = 0; it < 7; ++it) {
    int e = it * 1024 + tid * 4;
    if (e < NTILE * KMODES) {
      int row = (int)((unsigned)e / 100u);
      int col = e - row * 100;
      int a = row * LSTRIDE + col;
      float4 v = make_float4(lds[a], lds[a + 1], lds[a + 2], lds[a + 3]);
      *reinterpret_cast<float4*>(&out[base + e]) = v;
    }
  }
}

extern "C" void kernel_launch(void* const* d_in, const int* in_sizes, int n_in,
                              void* d_out, int out_size, void* d_ws, size_t ws_size,
                              hipStream_t stream) {
  const float* r = (const float*)d_in[0];
  const float* k = (const float*)d_in[1];
  float* out = (float*)d_out;
  int N = in_sizes[0];                   // 262144
  int blocks = N / NTILE;                // 4096
  sbf_kernel<<<blocks, 256, 0, stream>>>(r, k, out);
}

// Round 7
// 24.481 us; speedup vs baseline: 3.4221x; 1.0953x over previous
//
#include <hip/hip_runtime.h>
#include <math.h>

// SphericalBessel, closed form + zero-fill tail.
// x >= X_l: j_l = s*S_l(z) + c*C_l(z), z=1/x^2 (exact integer coeffs).
// x <  X_l: j_l ~ 0 (|j_l| <= ~5e-4 there; X_l balances f32 cancellation vs magnitude:
//           X_l = (eps*(2l-1)!!*(2l+1)!!)^(1/(2l+1)) = .088,.29,.61,1.01,1.48,2.00,2.55,3.14)
// u via v_rcp per mode (no LDS invk table). LDS staging rows stride 101, float4 flush.

static constexpr int KMODES = 100;
static constexpr int NTILE  = 64;
static constexpr int LSTRIDE = 101;
static constexpr float S2PI = 0.79788456080286536f; // sqrt(2/pi)

__device__ __forceinline__ float rcpf(float x) { return __builtin_amdgcn_rcpf(x); }

// closed-form polys in z = 1/x^2 (highest degree first):
// odd  L: j = s*z*sg(z) + c*u*gm(z);  even L: j = s*u*sg(z) + c*z*gm(z)
template<int L> struct CFc;
template<> struct CFc<2>{ static constexpr float sg[2]={3.f,-1.f};                                      static constexpr float gm[1]={-3.f}; };
template<> struct CFc<3>{ static constexpr float sg[2]={15.f,-6.f};                                     static constexpr float gm[2]={-15.f,1.f}; };
template<> struct CFc<4>{ static constexpr float sg[3]={105.f,-45.f,1.f};                               static constexpr float gm[2]={-105.f,10.f}; };
template<> struct CFc<5>{ static constexpr float sg[3]={945.f,-420.f,15.f};                             static constexpr float gm[3]={-945.f,105.f,-1.f}; };
template<> struct CFc<6>{ static constexpr float sg[4]={10395.f,-4725.f,210.f,-1.f};                    static constexpr float gm[3]={-10395.f,1260.f,-21.f}; };
template<> struct CFc<7>{ static constexpr float sg[4]={135135.f,-62370.f,3150.f,-28.f};                static constexpr float gm[4]={-135135.f,17325.f,-378.f,1.f}; };
template<> struct CFc<8>{ static constexpr float sg[5]={2027025.f,-945945.f,51975.f,-630.f,1.f};        static constexpr float gm[4]={-2027025.f,270270.f,-6930.f,36.f}; };
template<> struct CFc<9>{ static constexpr float sg[5]={34459425.f,-16216200.f,945945.f,-13860.f,45.f}; static constexpr float gm[5]={-34459425.f,4729725.f,-135135.f,990.f,-1.f}; };

__device__ __constant__ const float XCUT[10] =
  {0.f, 0.f, 0.088f, 0.29f, 0.61f, 1.01f, 1.48f, 2.00f, 2.55f, 3.14f};

template<int N>
__device__ __forceinline__ float polyH(float z, const float (&a)[N]) {
  float h = a[0];
#pragma unroll
  for (int i = 1; i < N; ++i) h = fmaf(h, z, a[i]);
  return h;
}

template<int L>
__device__ __forceinline__ void do_l(float rv, const float* __restrict__ kvec,
                                     float* ldsrow) {
#pragma unroll
  for (int m = 0; m < 2 * L + 1; ++m) {
    const int KK = L * L + m;
    float kv = kvec[KK];                 // uniform -> s_load
    float x  = rv * kv;
    float res;
    if constexpr (L == 0) {
      res = __sinf(x) * rcpf(x);         // j0
    } else {
      float u = rcpf(x);
      float s, c;
      __sincosf(x, &s, &c);
      float z = u * u;
      if constexpr (L == 1) {
        res = fmaf(s, z, -(c * u));      // j1: err < 5e-6 down to x=0.05, no guard
      } else {
        float sv = polyH(z, CFc<L>::sg);
        float gv = polyH(z, CFc<L>::gm);
        if constexpr (L & 1) res = fmaf(s * z, sv, (c * u) * gv);
        else                 res = fmaf(s * u, sv, (c * z) * gv);
        res = (x < XCUT[L]) ? 0.0f : res;  // zero-fill tail (|j_l|<=5e-4 there)
      }
    }
    ldsrow[KK] = res * (S2PI * kv);
  }
}

__global__ __launch_bounds__(256) void sbf_kernel(const float* __restrict__ r,
                                                  const float* __restrict__ kvec,
                                                  float* __restrict__ out) {
  __shared__ float lds[NTILE * LSTRIDE];   // 25.46 KB -> 6 blocks/CU
  int tid = threadIdx.x;
  int w = tid >> 6, lane = tid & 63;
  int n0 = blockIdx.x * NTILE;
  float rv = r[n0 + lane];
  float* ldsrow = &lds[lane * LSTRIDE];
  // cost-balanced partition (weights 469/445/435/451)
  if (w == 0)      { do_l<9>(rv, kvec, ldsrow); do_l<2>(rv, kvec, ldsrow); }
  else if (w == 1) { do_l<8>(rv, kvec, ldsrow); do_l<3>(rv, kvec, ldsrow); }
  else if (w == 2) { do_l<7>(rv, kvec, ldsrow); do_l<4>(rv, kvec, ldsrow); do_l<0>(rv, kvec, ldsrow); }
  else             { do_l<6>(rv, kvec, ldsrow); do_l<5>(rv, kvec, ldsrow); do_l<1>(rv, kvec, ldsrow); }
  __syncthreads();
  // flush: 6400 floats; padded-row gather (b32 reads), coalesced float4 global store
  size_t base = (size_t)n0 * KMODES;
#pragma unroll
  for (int it = 0; it < 7; ++it) {
    int e = it * 1024 + tid * 4;
    if (e < NTILE * KMODES) {
      int row = (int)((unsigned)e / 100u);
      int col = e - row * 100;
      int a = row * LSTRIDE + col;
      float4 v = make_float4(lds[a], lds[a + 1], lds[a + 2], lds[a + 3]);
      *reinterpret_cast<float4*>(&out[base + e]) = v;
    }
  }
}

extern "C" void kernel_launch(void* const* d_in, const int* in_sizes, int n_in,
                              void* d_out, int out_size, void* d_ws, size_t ws_size,
                              hipStream_t stream) {
  const float* r = (const float*)d_in[0];
  const float* k = (const float*)d_in[1];
  float* out = (float*)d_out;
  int N = in_sizes[0];                   // 262144
  int blocks = N / NTILE;                // 4096
  sbf_kernel<<<blocks, 256, 0, stream>>>(r, k, out);
}